// Round 1
// baseline (168.350 us; speedup 1.0000x reference)
//
#include <hip/hip_runtime.h>

// SimpleRetention: B=131072 batches of 14x14 fp32, processed as 4 sequential
// 7x7 chunks with a carried state r. One thread per batch; all per-batch
// state in registers. W/D are wave-uniform -> scalar loads.

#define NB 131072
#define CS 7

__global__ __launch_bounds__(256, 2) void retention_kernel(
    const float* __restrict__ X,    // [B,14,14]
    const float* __restrict__ WQ,   // [4,7,7]
    const float* __restrict__ WK,   // [4,7,7]
    const float* __restrict__ WV,   // [4,7,7]
    const float* __restrict__ Dm,   // [14,14]
    float* __restrict__ Out,        // [B,14,14]
    int B)
{
    int b = blockIdx.x * blockDim.x + threadIdx.x;
    if (b >= B) return;

    const float* xb = X + (size_t)b * 196;
    float*       ob = Out + (size_t)b * 196;

    // e[d] = 0.2^(d+1)
    const float e0 = 0.2f, e1 = 0.04f, e2 = 0.008f, e3 = 0.0016f,
                e4 = 3.2e-4f, e5 = 6.4e-5f, e6 = 1.28e-5f;
    const float evals[CS] = {e0, e1, e2, e3, e4, e5, e6};

    float r[CS][CS];
#pragma unroll
    for (int i = 0; i < CS; i++)
#pragma unroll
        for (int j = 0; j < CS; j++) r[i][j] = 0.0f;

    // chunk loop kept ROLLED (code size); inner loops fully unrolled so all
    // register arrays are statically indexed.
    for (int c = 0; c < 4; c++) {
        const int ro = (c >> 1) * CS;       // row offset 0 or 7
        const int co = (c & 1) * CS;        // col offset 0 or 7
        const float* wq = WQ + c * 49;      // uniform -> SGPR loads
        const float* wk = WK + c * 49;
        const float* wv = WV + c * 49;
        const float* xc = xb + ro * 14 + co;
        float*       oc = ob + ro * 14 + co;
        const float* dc = Dm + ro * 14 + co;

        // ---- load x chunk (49 dword loads, contiguous 784B block per thread)
        float x[CS][CS];
#pragma unroll
        for (int i = 0; i < CS; i++)
#pragma unroll
            for (int j = 0; j < CS; j++)
                x[i][j] = xc[i * 14 + j];

        // ---- K = x @ Wk, V = x @ Wv (column-blocked: 7 uniform W values live)
        float K[CS][CS], V[CS][CS];
#pragma unroll
        for (int j = 0; j < CS; j++) {
            float wc[CS];
#pragma unroll
            for (int k = 0; k < CS; k++) wc[k] = wk[k * CS + j];
#pragma unroll
            for (int i = 0; i < CS; i++) {
                float acc = 0.0f;
#pragma unroll
                for (int k = 0; k < CS; k++) acc = fmaf(x[i][k], wc[k], acc);
                K[i][j] = acc;
            }
        }
#pragma unroll
        for (int j = 0; j < CS; j++) {
            float wc[CS];
#pragma unroll
            for (int k = 0; k < CS; k++) wc[k] = wv[k * CS + j];
#pragma unroll
            for (int i = 0; i < CS; i++) {
                float acc = 0.0f;
#pragma unroll
                for (int k = 0; k < CS; k++) acc = fmaf(x[i][k], wc[k], acc);
                V[i][j] = acc;
            }
        }

        // ---- per output row d: qrow -> S row -> cross -> out row (Q never
        //      fully materialized; keeps VGPR peak ~225)
#pragma unroll
        for (int d = 0; d < CS; d++) {
            float q[CS];
#pragma unroll
            for (int j = 0; j < CS; j++) {
                float acc = 0.0f;
#pragma unroll
                for (int k = 0; k < CS; k++)
                    acc = fmaf(x[d][k], wq[k * CS + j], acc);
                q[j] = acc;
            }
            // s[k] = (q . K[k,:]) * D[d,k]
            float s[CS];
#pragma unroll
            for (int k = 0; k < CS; k++) {
                float acc = 0.0f;
#pragma unroll
                for (int j = 0; j < CS; j++) acc = fmaf(q[j], K[k][j], acc);
                s[k] = acc * dc[d * 14 + k];
            }
            // o[v] = e_d * (q @ r_prev)[v] + sum_k s[k]*V[k][v]
            float o[CS];
#pragma unroll
            for (int v = 0; v < CS; v++) {
                float acc = 0.0f;
#pragma unroll
                for (int j = 0; j < CS; j++) acc = fmaf(q[j], r[j][v], acc);
                o[v] = evals[d] * acc;
            }
#pragma unroll
            for (int k = 0; k < CS; k++)
#pragma unroll
                for (int v = 0; v < CS; v++)
                    o[v] = fmaf(s[k], V[k][v], o[v]);
#pragma unroll
            for (int v = 0; v < CS; v++)
                oc[d * 14 + v] = o[v];
        }

        // ---- r += K^T V
#pragma unroll
        for (int dd = 0; dd < CS; dd++)
#pragma unroll
            for (int v = 0; v < CS; v++) {
                float acc = r[dd][v];
#pragma unroll
                for (int k = 0; k < CS; k++)
                    acc = fmaf(K[k][dd], V[k][v], acc);
                r[dd][v] = acc;
            }
    }
}

extern "C" void kernel_launch(void* const* d_in, const int* in_sizes, int n_in,
                              void* d_out, int out_size, void* d_ws, size_t ws_size,
                              hipStream_t stream) {
    const float* X  = (const float*)d_in[0];
    const float* WQ = (const float*)d_in[1];
    const float* WK = (const float*)d_in[2];
    const float* WV = (const float*)d_in[3];
    const float* Dm = (const float*)d_in[4];
    float* Out = (float*)d_out;

    int B = in_sizes[0] / 196;
    int block = 256;
    int grid = (B + block - 1) / block;
    retention_kernel<<<grid, block, 0, stream>>>(X, WQ, WK, WV, Dm, Out, B);
}

// Round 2
// 136.115 us; speedup vs baseline: 1.2368x; 1.2368x over previous
//
#include <hip/hip_runtime.h>

// SimpleRetention: B=131072 batches of 14x14 fp32, 4 sequential 7x7 chunks
// with carried state r. One thread per batch for compute; global<->LDS
// staging in two row-halves (98 floats/batch) for fully coalesced HBM
// traffic. LDS stride 99 (odd) -> compute-phase lane-stride 3 mod 32 ->
// 2 lanes/bank = conflict-free.

#define CS 7
#define NB 128     // batches (threads) per block
#define HALFF 98   // floats per half per batch
#define STR 99     // padded LDS row stride

__global__ __launch_bounds__(128) void retention_kernel(
    const float* __restrict__ X,    // [B,14,14]
    const float* __restrict__ WQ,   // [4,7,7]
    const float* __restrict__ WK,   // [4,7,7]
    const float* __restrict__ WV,   // [4,7,7]
    const float* __restrict__ Dm,   // [14,14]
    float* __restrict__ Out,        // [B,14,14]
    int B)
{
    __shared__ float lds[NB * STR];   // 50688 B -> 3 blocks/CU
    const int tid = threadIdx.x;
    const int bbase = blockIdx.x * NB;
    const int nv = (B - bbase < NB) ? (B - bbase) : NB;

    const float evals[CS] = {0.2f, 0.04f, 0.008f, 0.0016f,
                             3.2e-4f, 6.4e-5f, 1.28e-5f};

    float r[CS][CS];
#pragma unroll
    for (int i = 0; i < CS; i++)
#pragma unroll
        for (int j = 0; j < CS; j++) r[i][j] = 0.0f;

    for (int h = 0; h < 2; ++h) {
        __syncthreads();   // protect LDS reuse across halves

        // ---- coalesced global -> LDS (float2): 49 x float2 per batch
        {
            const int n2 = nv * 49;
            for (int idx = tid; idx < n2; idx += NB) {
                int bl = idx / 49;
                int e2 = idx - bl * 49;
                const float* gp = X + (size_t)(bbase + bl) * 196 + h * HALFF + 2 * e2;
                float2 v = *reinterpret_cast<const float2*>(gp);
                float* lp = lds + bl * STR + 2 * e2;
                lp[0] = v.x;
                lp[1] = v.y;
            }
        }
        __syncthreads();

        // ---- compute 2 chunks of this half (chunk order 0,1,2,3 overall)
        if (tid < nv) {
            float* ldsb = lds + tid * STR;
            for (int cc = 0; cc < 2; ++cc) {
                const int c  = 2 * h + cc;
                const int co = cc * CS;                 // col offset in half
                const float* wq = WQ + c * 49;          // uniform -> SGPR
                const float* wk = WK + c * 49;
                const float* wv = WV + c * 49;
                const float* dc = Dm + (h * CS) * 14 + co;

                // x chunk: LDS -> regs (then LDS slots are dead -> reused for o)
                float x[CS][CS];
#pragma unroll
                for (int i = 0; i < CS; i++)
#pragma unroll
                    for (int j = 0; j < CS; j++)
                        x[i][j] = ldsb[i * 14 + co + j];

                // K = x @ Wk, V = x @ Wv
                float K[CS][CS], V[CS][CS];
#pragma unroll
                for (int j = 0; j < CS; j++) {
                    float wc[CS];
#pragma unroll
                    for (int k = 0; k < CS; k++) wc[k] = wk[k * CS + j];
#pragma unroll
                    for (int i = 0; i < CS; i++) {
                        float acc = 0.0f;
#pragma unroll
                        for (int k = 0; k < CS; k++) acc = fmaf(x[i][k], wc[k], acc);
                        K[i][j] = acc;
                    }
                }
#pragma unroll
                for (int j = 0; j < CS; j++) {
                    float wc[CS];
#pragma unroll
                    for (int k = 0; k < CS; k++) wc[k] = wv[k * CS + j];
#pragma unroll
                    for (int i = 0; i < CS; i++) {
                        float acc = 0.0f;
#pragma unroll
                        for (int k = 0; k < CS; k++) acc = fmaf(x[i][k], wc[k], acc);
                        V[i][j] = acc;
                    }
                }

                // per output row d: q -> s -> cross -> o ; o back into LDS
#pragma unroll
                for (int d = 0; d < CS; d++) {
                    float q[CS];
#pragma unroll
                    for (int j = 0; j < CS; j++) {
                        float acc = 0.0f;
#pragma unroll
                        for (int k = 0; k < CS; k++)
                            acc = fmaf(x[d][k], wq[k * CS + j], acc);
                        q[j] = acc;
                    }
                    float s[CS];
#pragma unroll
                    for (int k = 0; k < CS; k++) {
                        float acc = 0.0f;
#pragma unroll
                        for (int j = 0; j < CS; j++) acc = fmaf(q[j], K[k][j], acc);
                        s[k] = acc * dc[d * 14 + k];
                    }
                    float o[CS];
#pragma unroll
                    for (int v = 0; v < CS; v++) {
                        float acc = 0.0f;
#pragma unroll
                        for (int j = 0; j < CS; j++) acc = fmaf(q[j], r[j][v], acc);
                        o[v] = evals[d] * acc;
                    }
#pragma unroll
                    for (int k = 0; k < CS; k++)
#pragma unroll
                        for (int v = 0; v < CS; v++)
                            o[v] = fmaf(s[k], V[k][v], o[v]);
#pragma unroll
                    for (int v = 0; v < CS; v++)
                        ldsb[d * 14 + co + v] = o[v];
                }

                // r += K^T V  (after cross used r_prev)
#pragma unroll
                for (int dd = 0; dd < CS; dd++)
#pragma unroll
                    for (int v = 0; v < CS; v++) {
                        float acc = r[dd][v];
#pragma unroll
                        for (int k = 0; k < CS; k++)
                            acc = fmaf(K[k][dd], V[k][v], acc);
                        r[dd][v] = acc;
                    }
            }
        }
        __syncthreads();

        // ---- coalesced LDS -> global (float2)
        {
            const int n2 = nv * 49;
            for (int idx = tid; idx < n2; idx += NB) {
                int bl = idx / 49;
                int e2 = idx - bl * 49;
                float* lp = lds + bl * STR + 2 * e2;
                float2 v;
                v.x = lp[0];
                v.y = lp[1];
                *reinterpret_cast<float2*>(Out + (size_t)(bbase + bl) * 196 + h * HALFF + 2 * e2) = v;
            }
        }
    }
}

extern "C" void kernel_launch(void* const* d_in, const int* in_sizes, int n_in,
                              void* d_out, int out_size, void* d_ws, size_t ws_size,
                              hipStream_t stream) {
    const float* X  = (const float*)d_in[0];
    const float* WQ = (const float*)d_in[1];
    const float* WK = (const float*)d_in[2];
    const float* WV = (const float*)d_in[3];
    const float* Dm = (const float*)d_in[4];
    float* Out = (float*)d_out;

    int B = in_sizes[0] / 196;
    int grid = (B + NB - 1) / NB;
    retention_kernel<<<grid, NB, 0, stream>>>(X, WQ, WK, WV, Dm, Out, B);
}